// Round 7
// baseline (552.080 us; speedup 1.0000x reference)
//
#include <hip/hip_runtime.h>

// 2-layer GCN. CSR via bucketed counting sort (few-block bin pass to cut
// bucket-atomic contention). Aggregations: single-pass full-row gathers
// (empirical ceiling: logical gather bytes / ~7.8 TB/s), uint4 payloads,
// packed f32x2 accumulation, 32-bit byte offsets.

typedef short          s16x8 __attribute__((ext_vector_type(8)));
typedef float          f32x4 __attribute__((ext_vector_type(4)));
typedef float          f32x2 __attribute__((ext_vector_type(2)));
typedef unsigned short u16x8 __attribute__((ext_vector_type(8)));
typedef unsigned short u16x4 __attribute__((ext_vector_type(4)));

__device__ __forceinline__ float bf2f(unsigned short u) {
  union { unsigned int i; float f; } x; x.i = ((unsigned int)u) << 16; return x.f;
}
__device__ __forceinline__ unsigned short f2bf(float f) {
  union { float f; unsigned int i; } x; x.f = f;
  unsigned int r = x.i + 0x7FFFu + ((x.i >> 16) & 1u);
  return (unsigned short)(r >> 16);
}
// accumulate 2 bf16 features (packed in one dword) into f32x2
__device__ __forceinline__ void acc2(f32x2& a, unsigned int pair) {
  union { unsigned int u; float f; } lo, hi;
  lo.u = pair << 16;
  hi.u = pair & 0xFFFF0000u;
  f32x2 v = {lo.f, hi.f};
  a += v;
}

// ---------------- CSR build (bucketed counting sort) ----------------

#define NBUCK_PAD 1024
#define BIN_CHUNK 32768

__global__ __launch_bounds__(256) void k_hist(const int* __restrict__ dst,
                                              int* __restrict__ bcnt, int E) {
  __shared__ int h[NBUCK_PAD];
  int t = threadIdx.x;
  for (int i = t; i < NBUCK_PAD; i += 256) h[i] = 0;
  __syncthreads();
  int n4 = E >> 2;
  int stride = gridDim.x * 256;
  const int4* d4 = (const int4*)dst;
  for (int e = blockIdx.x * 256 + t; e < n4; e += stride) {
    int4 v = d4[e];
    atomicAdd(&h[v.x >> 7], 1);
    atomicAdd(&h[v.y >> 7], 1);
    atomicAdd(&h[v.z >> 7], 1);
    atomicAdd(&h[v.w >> 7], 1);
  }
  if (blockIdx.x == 0) {
    for (int e = n4 * 4 + t; e < E; e += 256) atomicAdd(&h[dst[e] >> 7], 1);
  }
  __syncthreads();
  for (int i = t; i < NBUCK_PAD; i += 256) {
    int v = h[i];
    if (v) atomicAdd(bcnt + i, v);
  }
}

__global__ void k_bscan(const int* __restrict__ bcnt, int* __restrict__ bptr,
                        int* __restrict__ bcur, int* __restrict__ rowptr, int M, int E) {
  __shared__ int sh[NBUCK_PAD];
  int t = threadIdx.x;
  int v = bcnt[t];
  sh[t] = v; __syncthreads();
  int x = v;
  for (int off = 1; off < NBUCK_PAD; off <<= 1) {
    int y = (t >= off) ? sh[t - off] : 0;
    __syncthreads();
    x += y; sh[t] = x;
    __syncthreads();
  }
  bptr[t] = x - v;
  bcur[t] = x - v;
  if (t == NBUCK_PAD - 1) bptr[NBUCK_PAD] = x;
  if (t == 0) rowptr[M] = E;
}

__global__ __launch_bounds__(256) void k_bin(const int* __restrict__ src,
                                             const int* __restrict__ dst,
                                             int* __restrict__ bcur,
                                             unsigned int* __restrict__ binned, int E) {
  __shared__ int hist[NBUCK_PAD];
  __shared__ int base[NBUCK_PAD];
  int t = threadIdx.x;
  int e0 = blockIdx.x * BIN_CHUNK;
  int e1 = min(e0 + BIN_CHUNK, E);
  for (int i = t; i < NBUCK_PAD; i += 256) hist[i] = 0;
  __syncthreads();
  for (int e = e0 + t; e < e1; e += 256) atomicAdd(&hist[dst[e] >> 7], 1);
  __syncthreads();
  for (int i = t; i < NBUCK_PAD; i += 256) {
    int h = hist[i];
    base[i] = h ? atomicAdd(bcur + i, h) : 0;
    hist[i] = 0;
  }
  __syncthreads();
  for (int e = e0 + t; e < e1; e += 256) {
    int d = dst[e], s = src[e];
    int b = d >> 7;
    int p = base[b] + atomicAdd(&hist[b], 1);
    binned[p] = ((unsigned)(d & 127) << 17) | (unsigned)s;
  }
}

__global__ __launch_bounds__(256) void k_csr(const unsigned int* __restrict__ binned,
                                             const int* __restrict__ bptr,
                                             int* __restrict__ rowptr,
                                             float* __restrict__ dinv,
                                             int* __restrict__ col, int M) {
  __shared__ int deg[128];
  __shared__ int sc[128];
  __shared__ int cur[128];
  int b = blockIdx.x, t = threadIdx.x;
  int n0 = b << 7;
  int nn = min(128, M - n0);
  int e0 = bptr[b], e1 = bptr[b + 1];
  if (t < 128) deg[t] = 0;
  __syncthreads();
  for (int e = e0 + t; e < e1; e += 256) atomicAdd(&deg[(binned[e] >> 17) & 127], 1);
  __syncthreads();
  if (t < 128) sc[t] = deg[t];
  __syncthreads();
  for (int off = 1; off < 128; off <<= 1) {
    int y = 0;
    if (t < 128 && t >= off) y = sc[t - off];
    __syncthreads();
    if (t < 128) sc[t] += y;
    __syncthreads();
  }
  if (t < nn) {
    int excl = sc[t] - deg[t];
    rowptr[n0 + t] = e0 + excl;
    dinv[n0 + t] = rsqrtf((float)(deg[t] + 1));
    cur[t] = excl;
  }
  __syncthreads();
  for (int e = e0 + t; e < e1; e += 256) {
    unsigned v = binned[e];
    int dl = (v >> 17) & 127;
    int p = e0 + atomicAdd(&cur[dl], 1);
    col[p] = (int)(v & 0x1FFFFu);
  }
}

// ---------------- weight transpose+convert ----------------

__global__ void k_cvt_w(const float* __restrict__ W1, const float* __restrict__ W2,
                        unsigned short* __restrict__ w1t, unsigned short* __restrict__ w2t) {
  int i = blockIdx.x * 256 + threadIdx.x;
  if (i < 256 * 256) {
    int k = i >> 8, n = i & 255;
    w1t[n * 256 + k] = f2bf(W1[i]);
  } else {
    int j = i - 256 * 256;
    if (j < 256 * 128) {
      int k = j >> 7, n = j & 127;
      w2t[n * 256 + k] = f2bf(W2[j]);
    }
  }
}

// ---------------- GEMM1: g1 = dinv .* (x @ W1), row-major [M][256] ----------------

__device__ __forceinline__ int swz4(int row, int kc) { return kc ^ ((row & 3) << 3); }

__global__ __launch_bounds__(512) void k_gemm1(
    const float* __restrict__ X, const unsigned short* __restrict__ Bt,
    const float* __restrict__ dinv, unsigned short* __restrict__ G, int M) {
  const int K = 256;
  __shared__ short lA[128 * 32];
  __shared__ short lB[256 * 32];
  int tid = threadIdx.x;
  int wid = tid >> 6, lane = tid & 63;
  int wm = wid >> 2, wn = wid & 3;
  int l15 = lane & 15;
  int lkg = (lane >> 4) * 8;
  int bm = blockIdx.x * 128;

  f32x4 acc[4][4] = {};

  for (int kt = 0; kt < 8; ++kt) {
    int k0 = kt * 32;
    __syncthreads();
#pragma unroll
    for (int h = 0; h < 2; ++h) {
      int cid = tid + h * 512;
      int r = cid >> 3, c4 = (cid & 7) * 4;
      int gr = bm + r;
      float4 v = {0.f, 0.f, 0.f, 0.f};
      if (gr < M) v = *(const float4*)(X + (size_t)gr * K + k0 + c4);
      u16x4 o; o[0] = f2bf(v.x); o[1] = f2bf(v.y); o[2] = f2bf(v.z); o[3] = f2bf(v.w);
      *(u16x4*)(&lA[r * 32 + swz4(r, c4)]) = o;
    }
#pragma unroll
    for (int h = 0; h < 2; ++h) {
      int cid = tid + h * 512;
      int n = cid >> 2, kc = (cid & 3) * 8;
      s16x8 v = *(const s16x8*)(Bt + (size_t)n * K + k0 + kc);
      *(s16x8*)(&lB[n * 32 + swz4(n, kc)]) = v;
    }
    __syncthreads();

    s16x8 af[4], bfr[4];
#pragma unroll
    for (int mi = 0; mi < 4; ++mi) {
      int r = wm * 64 + mi * 16 + l15;
      af[mi] = *(const s16x8*)(&lA[r * 32 + swz4(r, lkg)]);
    }
#pragma unroll
    for (int ni = 0; ni < 4; ++ni) {
      int c = wn * 64 + ni * 16 + l15;
      bfr[ni] = *(const s16x8*)(&lB[c * 32 + swz4(c, lkg)]);
    }
#pragma unroll
    for (int mi = 0; mi < 4; ++mi)
#pragma unroll
      for (int ni = 0; ni < 4; ++ni)
        acc[mi][ni] = __builtin_amdgcn_mfma_f32_16x16x32_bf16(af[mi], bfr[ni], acc[mi][ni], 0, 0, 0);
  }

#pragma unroll
  for (int mi = 0; mi < 4; ++mi) {
    int mrow0 = bm + wm * 64 + mi * 16 + (lane >> 4) * 4;
#pragma unroll
    for (int j = 0; j < 4; ++j) {
      int m = mrow0 + j;
      if (m < M) {
        float dv = dinv[m];
#pragma unroll
        for (int ni = 0; ni < 4; ++ni)
          G[(size_t)m * 256 + wn * 64 + ni * 16 + l15] = f2bf(acc[mi][ni][j] * dv);
      }
    }
  }
}

// ---------------- GEMM2: g2 = dinv .* (hid @ W2), row-major [M][128] ----------------

__global__ __launch_bounds__(512) void k_gemm2(
    const unsigned short* __restrict__ A, const unsigned short* __restrict__ Bt,
    const float* __restrict__ dinv, unsigned short* __restrict__ G, int M) {
  const int K = 256;
  __shared__ short lA[128 * 32];
  __shared__ short lB[128 * 32];
  int tid = threadIdx.x;
  int wid = tid >> 6, lane = tid & 63;
  int wm = wid >> 2, wn = wid & 3;
  int l15 = lane & 15;
  int lkg = (lane >> 4) * 8;
  int bm = blockIdx.x * 128;

  f32x4 acc[4][2] = {};

  for (int kt = 0; kt < 8; ++kt) {
    int k0 = kt * 32;
    __syncthreads();
    {
      int r = tid >> 2, kc = (tid & 3) * 8;
      int gr = bm + r;
      s16x8 v = {0, 0, 0, 0, 0, 0, 0, 0};
      if (gr < M) v = *(const s16x8*)(A + (size_t)gr * K + k0 + kc);
      *(s16x8*)(&lA[r * 32 + swz4(r, kc)]) = v;
    }
    {
      int n = tid >> 2, kc = (tid & 3) * 8;
      s16x8 v = *(const s16x8*)(Bt + (size_t)n * K + k0 + kc);
      *(s16x8*)(&lB[n * 32 + swz4(n, kc)]) = v;
    }
    __syncthreads();

    s16x8 af[4], bfr[2];
#pragma unroll
    for (int mi = 0; mi < 4; ++mi) {
      int r = wm * 64 + mi * 16 + l15;
      af[mi] = *(const s16x8*)(&lA[r * 32 + swz4(r, lkg)]);
    }
#pragma unroll
    for (int ni = 0; ni < 2; ++ni) {
      int c = wn * 32 + ni * 16 + l15;
      bfr[ni] = *(const s16x8*)(&lB[c * 32 + swz4(c, lkg)]);
    }
#pragma unroll
    for (int mi = 0; mi < 4; ++mi)
#pragma unroll
      for (int ni = 0; ni < 2; ++ni)
        acc[mi][ni] = __builtin_amdgcn_mfma_f32_16x16x32_bf16(af[mi], bfr[ni], acc[mi][ni], 0, 0, 0);
  }

#pragma unroll
  for (int mi = 0; mi < 4; ++mi) {
    int mrow0 = bm + wm * 64 + mi * 16 + (lane >> 4) * 4;
#pragma unroll
    for (int j = 0; j < 4; ++j) {
      int m = mrow0 + j;
      if (m < M) {
        float dv = dinv[m];
#pragma unroll
        for (int ni = 0; ni < 2; ++ni)
          G[(size_t)m * 128 + wn * 32 + ni * 16 + l15] = f2bf(acc[mi][ni][j] * dv);
      }
    }
  }
}

// ---------------- agg layer 1: 256 feats (512B rows), single pass ----------------
// One wave per node. 32 lanes x 16B per row; slot = lane>>5 (2 edges/inst).

__global__ __launch_bounds__(256) void k_agg256(
    const unsigned short* __restrict__ G, const int* __restrict__ rowptr,
    const int* __restrict__ col, const float* __restrict__ dinv,
    const float* __restrict__ bias, unsigned short* __restrict__ H, int M) {
  int lane = threadIdx.x & 63;
  int v = (blockIdx.x << 2) + (threadIdx.x >> 6);
  if (v >= M) return;
  int slot = lane >> 5;              // 0..1
  int l32 = lane & 31;
  int boff = l32 * 16;               // byte offset within 512B row
  const char* Gb = (const char*)G;
  f32x2 a[4] = {};
  if (slot == 0) {
    uint4 w = *(const uint4*)(Gb + (((unsigned)v) << 9) + boff);
    acc2(a[0], w.x); acc2(a[1], w.y); acc2(a[2], w.z); acc2(a[3], w.w);
  }
  int jb = rowptr[v], je = rowptr[v + 1];
  int j = jb;
  for (; j + 4 <= je; j += 4) {
    unsigned u0 = (unsigned)col[j + slot];
    unsigned u1 = (unsigned)col[j + 2 + slot];
    uint4 w0 = *(const uint4*)(Gb + (u0 << 9) + boff);
    uint4 w1 = *(const uint4*)(Gb + (u1 << 9) + boff);
    acc2(a[0], w0.x); acc2(a[1], w0.y); acc2(a[2], w0.z); acc2(a[3], w0.w);
    acc2(a[0], w1.x); acc2(a[1], w1.y); acc2(a[2], w1.z); acc2(a[3], w1.w);
  }
  for (; j + 2 <= je; j += 2) {
    unsigned u = (unsigned)col[j + slot];
    uint4 w = *(const uint4*)(Gb + (u << 9) + boff);
    acc2(a[0], w.x); acc2(a[1], w.y); acc2(a[2], w.z); acc2(a[3], w.w);
  }
  if (j < je && slot == 0) {
    unsigned u = (unsigned)col[j];
    uint4 w = *(const uint4*)(Gb + (u << 9) + boff);
    acc2(a[0], w.x); acc2(a[1], w.y); acc2(a[2], w.z); acc2(a[3], w.w);
  }
#pragma unroll
  for (int k = 0; k < 4; ++k) {
    a[k].x += __shfl_xor(a[k].x, 32, 64);
    a[k].y += __shfl_xor(a[k].y, 32, 64);
  }
  if (slot == 0) {
    float dv = dinv[v];
    const float* bp = bias + l32 * 8;
    u16x8 o;
#pragma unroll
    for (int k = 0; k < 4; ++k) {
      o[2 * k]     = f2bf(fmaxf(fmaf(dv, a[k].x, bp[2 * k]),     0.f));
      o[2 * k + 1] = f2bf(fmaxf(fmaf(dv, a[k].y, bp[2 * k + 1]), 0.f));
    }
    *(u16x8*)(H + (size_t)v * 256 + l32 * 8) = o;
  }
}

// ---------------- agg layer 2: 128 feats (256B rows), single pass, fp32 out ----------------
// One wave per node. 16 lanes x 16B per row; slot = lane>>4 (4 edges/inst).

__global__ __launch_bounds__(256) void k_agg128(
    const unsigned short* __restrict__ G, const int* __restrict__ rowptr,
    const int* __restrict__ col, const float* __restrict__ dinv,
    const float* __restrict__ bias, float* __restrict__ Out, int M) {
  int lane = threadIdx.x & 63;
  int v = (blockIdx.x << 2) + (threadIdx.x >> 6);
  if (v >= M) return;
  int slot = lane >> 4;              // 0..3
  int l16 = lane & 15;
  int boff = l16 * 16;               // byte offset within 256B row
  const char* Gb = (const char*)G;
  f32x2 a[4] = {};
  if (slot == 0) {
    uint4 w = *(const uint4*)(Gb + (((unsigned)v) << 8) + boff);
    acc2(a[0], w.x); acc2(a[1], w.y); acc2(a[2], w.z); acc2(a[3], w.w);
  }
  int jb = rowptr[v], je = rowptr[v + 1];
  int j = jb;
  for (; j + 8 <= je; j += 8) {
    unsigned u0 = (unsigned)col[j + slot];
    unsigned u1 = (unsigned)col[j + 4 + slot];
    uint4 w0 = *(const uint4*)(Gb + (u0 << 8) + boff);
    uint4 w1 = *(const uint4*)(Gb + (u1 << 8) + boff);
    acc2(a[0], w0.x); acc2(a[1], w0.y); acc2(a[2], w0.z); acc2(a[3], w0.w);
    acc2(a[0], w1.x); acc2(a[1], w1.y); acc2(a[2], w1.z); acc2(a[3], w1.w);
  }
  for (; j + 4 <= je; j += 4) {
    unsigned u = (unsigned)col[j + slot];
    uint4 w = *(const uint4*)(Gb + (u << 8) + boff);
    acc2(a[0], w.x); acc2(a[1], w.y); acc2(a[2], w.z); acc2(a[3], w.w);
  }
  int rem = je - j;
  if (slot < rem) {
    unsigned u = (unsigned)col[j + slot];
    uint4 w = *(const uint4*)(Gb + (u << 8) + boff);
    acc2(a[0], w.x); acc2(a[1], w.y); acc2(a[2], w.z); acc2(a[3], w.w);
  }
#pragma unroll
  for (int k = 0; k < 4; ++k) {
    a[k].x += __shfl_xor(a[k].x, 16, 64);
    a[k].y += __shfl_xor(a[k].y, 16, 64);
    a[k].x += __shfl_xor(a[k].x, 32, 64);
    a[k].y += __shfl_xor(a[k].y, 32, 64);
  }
  if (slot == 0) {
    float dv = dinv[v];
    const float* bp = bias + l16 * 8;
    float4 r0, r1;
    r0.x = fmaxf(fmaf(dv, a[0].x, bp[0]), 0.f);
    r0.y = fmaxf(fmaf(dv, a[0].y, bp[1]), 0.f);
    r0.z = fmaxf(fmaf(dv, a[1].x, bp[2]), 0.f);
    r0.w = fmaxf(fmaf(dv, a[1].y, bp[3]), 0.f);
    r1.x = fmaxf(fmaf(dv, a[2].x, bp[4]), 0.f);
    r1.y = fmaxf(fmaf(dv, a[2].y, bp[5]), 0.f);
    r1.z = fmaxf(fmaf(dv, a[3].x, bp[6]), 0.f);
    r1.w = fmaxf(fmaf(dv, a[3].y, bp[7]), 0.f);
    float* op = Out + (size_t)v * 128 + l16 * 8;
    *(float4*)op = r0;
    *(float4*)(op + 4) = r1;
  }
}

// ---------------- launch ----------------

extern "C" void kernel_launch(void* const* d_in, const int* in_sizes, int n_in,
                              void* d_out, int out_size, void* d_ws, size_t ws_size,
                              hipStream_t stream) {
  const float* x  = (const float*)d_in[0];
  const float* W1 = (const float*)d_in[1];
  const float* b1 = (const float*)d_in[2];
  const float* W2 = (const float*)d_in[3];
  const float* b2 = (const float*)d_in[4];
  const int*   ei = (const int*)d_in[5];

  const int D_IN = 256, D_HID = 256, D_OUT = 128;
  const int M = in_sizes[0] / D_IN;    // 100000
  const int E = in_sizes[5] / 2;       // 3200000
  const int* src = ei;
  const int* dst = ei + E;

  char* p = (char*)d_ws;
  auto alloc = [&](size_t bytes) { void* r = (void*)p; p += (bytes + 255) & ~(size_t)255; return r; };
  float* dinv = (float*)alloc((size_t)M * 4);
  int* rowptr = (int*)alloc((size_t)(M + 1) * 4);
  int* bcnt   = (int*)alloc(NBUCK_PAD * 4);
  int* bptr   = (int*)alloc((NBUCK_PAD + 1) * 4);
  int* bcur   = (int*)alloc(NBUCK_PAD * 4);
  int* colx   = (int*)alloc((size_t)E * 4);
  unsigned short* w1t = (unsigned short*)alloc((size_t)D_HID * D_IN * 2);
  unsigned short* w2t = (unsigned short*)alloc((size_t)D_OUT * D_HID * 2);
  unsigned short* g1  = (unsigned short*)alloc((size_t)M * D_HID * 2);   // [M][256]
  unsigned short* hid = (unsigned short*)alloc((size_t)M * D_HID * 2);   // [M][256]
  unsigned short* g2  = (unsigned short*)alloc((size_t)M * D_OUT * 2);   // [M][128]
  unsigned int* binned = (unsigned int*)g1;   // g1 written only after k_csr consumed binned

  int nbuck = (M + 127) >> 7;                     // 782
  int nbin  = (E + BIN_CHUNK - 1) / BIN_CHUNK;    // 98
  int nb4   = (M + 3) / 4;

  hipMemsetAsync(bcnt, 0, NBUCK_PAD * 4, stream);
  k_hist <<<104, 256, 0, stream>>>(dst, bcnt, E);
  k_bscan<<<1, NBUCK_PAD, 0, stream>>>(bcnt, bptr, bcur, rowptr, M, E);
  k_bin  <<<nbin, 256, 0, stream>>>(src, dst, bcur, binned, E);
  k_csr  <<<nbuck, 256, 0, stream>>>(binned, bptr, rowptr, dinv, colx, M);

  k_cvt_w<<<(256 * 256 + 256 * 128 + 255) / 256, 256, 0, stream>>>(W1, W2, w1t, w2t);

  k_gemm1 <<<nbuck, 512, 0, stream>>>(x, w1t, dinv, g1, M);
  k_agg256<<<nb4, 256, 0, stream>>>(g1, rowptr, colx, dinv, b1, hid, M);
  k_gemm2 <<<nbuck, 512, 0, stream>>>(hid, w2t, dinv, g2, M);
  k_agg128<<<nb4, 256, 0, stream>>>(g2, rowptr, colx, dinv, b2, (float*)d_out, M);
}

// Round 9
// 506.379 us; speedup vs baseline: 1.0903x; 1.0903x over previous
//
#include <hip/hip_runtime.h>

// 2-layer GCN. CSR via bucketed counting sort. Aggregations: single-pass
// full-row gathers pinned at the L2-miss-path ceiling (time = FETCH/3.5TB/s);
// col stream + output stores are nontemporal to avoid L2 pollution.

typedef short          s16x8 __attribute__((ext_vector_type(8)));
typedef float          f32x4 __attribute__((ext_vector_type(4)));
typedef float          f32x2 __attribute__((ext_vector_type(2)));
typedef unsigned short u16x8 __attribute__((ext_vector_type(8)));
typedef unsigned short u16x4 __attribute__((ext_vector_type(4)));

__device__ __forceinline__ float bf2f(unsigned short u) {
  union { unsigned int i; float f; } x; x.i = ((unsigned int)u) << 16; return x.f;
}
__device__ __forceinline__ unsigned short f2bf(float f) {
  union { float f; unsigned int i; } x; x.f = f;
  unsigned int r = x.i + 0x7FFFu + ((x.i >> 16) & 1u);
  return (unsigned short)(r >> 16);
}
__device__ __forceinline__ void acc2(f32x2& a, unsigned int pair) {
  union { unsigned int u; float f; } lo, hi;
  lo.u = pair << 16;
  hi.u = pair & 0xFFFF0000u;
  f32x2 v = {lo.f, hi.f};
  a += v;
}

// ---------------- CSR build (bucketed counting sort) ----------------

#define NBUCK_PAD 1024
#define BIN_CHUNK 8192

__global__ __launch_bounds__(256) void k_hist(const int* __restrict__ dst,
                                              int* __restrict__ bcnt, int E) {
  __shared__ int h[NBUCK_PAD];
  int t = threadIdx.x;
  for (int i = t; i < NBUCK_PAD; i += 256) h[i] = 0;
  __syncthreads();
  int n4 = E >> 2;
  int stride = gridDim.x * 256;
  const int4* d4 = (const int4*)dst;
  for (int e = blockIdx.x * 256 + t; e < n4; e += stride) {
    int4 v = d4[e];
    atomicAdd(&h[v.x >> 7], 1);
    atomicAdd(&h[v.y >> 7], 1);
    atomicAdd(&h[v.z >> 7], 1);
    atomicAdd(&h[v.w >> 7], 1);
  }
  if (blockIdx.x == 0) {
    for (int e = n4 * 4 + t; e < E; e += 256) atomicAdd(&h[dst[e] >> 7], 1);
  }
  __syncthreads();
  for (int i = t; i < NBUCK_PAD; i += 256) {
    int v = h[i];
    if (v) atomicAdd(bcnt + i, v);
  }
}

__global__ void k_bscan(const int* __restrict__ bcnt, int* __restrict__ bptr,
                        int* __restrict__ bcur, int* __restrict__ rowptr, int M, int E) {
  __shared__ int sh[NBUCK_PAD];
  int t = threadIdx.x;
  int v = bcnt[t];
  sh[t] = v; __syncthreads();
  int x = v;
  for (int off = 1; off < NBUCK_PAD; off <<= 1) {
    int y = (t >= off) ? sh[t - off] : 0;
    __syncthreads();
    x += y; sh[t] = x;
    __syncthreads();
  }
  bptr[t] = x - v;
  bcur[t] = x - v;
  if (t == NBUCK_PAD - 1) bptr[NBUCK_PAD] = x;
  if (t == 0) rowptr[M] = E;
}

__global__ __launch_bounds__(256) void k_bin(const int* __restrict__ src,
                                             const int* __restrict__ dst,
                                             int* __restrict__ bcur,
                                             unsigned int* __restrict__ binned, int E) {
  __shared__ int hist[NBUCK_PAD];
  __shared__ int base[NBUCK_PAD];
  int t = threadIdx.x;
  int e0 = blockIdx.x * BIN_CHUNK;
  int e1 = min(e0 + BIN_CHUNK, E);
  for (int i = t; i < NBUCK_PAD; i += 256) hist[i] = 0;
  __syncthreads();
  for (int e = e0 + t; e < e1; e += 256) atomicAdd(&hist[dst[e] >> 7], 1);
  __syncthreads();
  for (int i = t; i < NBUCK_PAD; i += 256) {
    int h = hist[i];
    base[i] = h ? atomicAdd(bcur + i, h) : 0;
    hist[i] = 0;
  }
  __syncthreads();
  for (int e = e0 + t; e < e1; e += 256) {
    int d = dst[e], s = src[e];
    int b = d >> 7;
    int p = base[b] + atomicAdd(&hist[b], 1);
    binned[p] = ((unsigned)(d & 127) << 17) | (unsigned)s;
  }
}

__global__ __launch_bounds__(256) void k_csr(const unsigned int* __restrict__ binned,
                                             const int* __restrict__ bptr,
                                             int* __restrict__ rowptr,
                                             float* __restrict__ dinv,
                                             int* __restrict__ col, int M) {
  __shared__ int deg[128];
  __shared__ int sc[128];
  __shared__ int cur[128];
  int b = blockIdx.x, t = threadIdx.x;
  int n0 = b << 7;
  int nn = min(128, M - n0);
  int e0 = bptr[b], e1 = bptr[b + 1];
  if (t < 128) deg[t] = 0;
  __syncthreads();
  for (int e = e0 + t; e < e1; e += 256) atomicAdd(&deg[(binned[e] >> 17) & 127], 1);
  __syncthreads();
  if (t < 128) sc[t] = deg[t];
  __syncthreads();
  for (int off = 1; off < 128; off <<= 1) {
    int y = 0;
    if (t < 128 && t >= off) y = sc[t - off];
    __syncthreads();
    if (t < 128) sc[t] += y;
    __syncthreads();
  }
  if (t < nn) {
    int excl = sc[t] - deg[t];
    rowptr[n0 + t] = e0 + excl;
    dinv[n0 + t] = rsqrtf((float)(deg[t] + 1));
    cur[t] = excl;
  }
  __syncthreads();
  for (int e = e0 + t; e < e1; e += 256) {
    unsigned v = binned[e];
    int dl = (v >> 17) & 127;
    int p = e0 + atomicAdd(&cur[dl], 1);
    col[p] = (int)(v & 0x1FFFFu);
  }
}

// ---------------- weight transpose+convert ----------------

__global__ void k_cvt_w(const float* __restrict__ W1, const float* __restrict__ W2,
                        unsigned short* __restrict__ w1t, unsigned short* __restrict__ w2t) {
  int i = blockIdx.x * 256 + threadIdx.x;
  if (i < 256 * 256) {
    int k = i >> 8, n = i & 255;
    w1t[n * 256 + k] = f2bf(W1[i]);
  } else {
    int j = i - 256 * 256;
    if (j < 256 * 128) {
      int k = j >> 7, n = j & 127;
      w2t[n * 256 + k] = f2bf(W2[j]);
    }
  }
}

// ---------------- GEMM1: g1 = dinv .* (x @ W1), tile 64x256, 256 thr ----------------

__device__ __forceinline__ int swz4(int row, int kc) { return kc ^ ((row & 3) << 3); }

__global__ __launch_bounds__(256) void k_gemm1(
    const float* __restrict__ X, const unsigned short* __restrict__ Bt,
    const float* __restrict__ dinv, unsigned short* __restrict__ G, int M) {
  const int K = 256;
  __shared__ short lA[64 * 32];    // 4 KB
  __shared__ short lB[256 * 32];   // 16 KB
  int tid = threadIdx.x;
  int wid = tid >> 6, lane = tid & 63;
  int wm = wid >> 1, wn = wid & 1;
  int l15 = lane & 15;
  int lkg = (lane >> 4) * 8;
  int bm = blockIdx.x * 64;

  f32x4 acc[2][8] = {};

  for (int kt = 0; kt < 8; ++kt) {
    int k0 = kt * 32;
    __syncthreads();
    // stage A: 64 rows x 32 k fp32 -> bf16; 512 float4-chunks
#pragma unroll
    for (int h = 0; h < 2; ++h) {
      int cid = tid + h * 256;
      int r = cid >> 3, c4 = (cid & 7) * 4;
      int gr = bm + r;
      float4 v = {0.f, 0.f, 0.f, 0.f};
      if (gr < M) v = *(const float4*)(X + (size_t)gr * K + k0 + c4);
      u16x4 o; o[0] = f2bf(v.x); o[1] = f2bf(v.y); o[2] = f2bf(v.z); o[3] = f2bf(v.w);
      *(u16x4*)(&lA[r * 32 + swz4(r, c4)]) = o;
    }
    // stage B: 256 n-rows x 32 k bf16; 1024 s16x8-chunks
#pragma unroll
    for (int h = 0; h < 4; ++h) {
      int cid = tid + h * 256;
      int n = cid >> 2, kc = (cid & 3) * 8;
      s16x8 v = *(const s16x8*)(Bt + (size_t)n * K + k0 + kc);
      *(s16x8*)(&lB[n * 32 + swz4(n, kc)]) = v;
    }
    __syncthreads();

    s16x8 af[2], bfr[8];
#pragma unroll
    for (int mi = 0; mi < 2; ++mi) {
      int r = wm * 32 + mi * 16 + l15;
      af[mi] = *(const s16x8*)(&lA[r * 32 + swz4(r, lkg)]);
    }
#pragma unroll
    for (int ni = 0; ni < 8; ++ni) {
      int c = wn * 128 + ni * 16 + l15;
      bfr[ni] = *(const s16x8*)(&lB[c * 32 + swz4(c, lkg)]);
    }
#pragma unroll
    for (int mi = 0; mi < 2; ++mi)
#pragma unroll
      for (int ni = 0; ni < 8; ++ni)
        acc[mi][ni] = __builtin_amdgcn_mfma_f32_16x16x32_bf16(af[mi], bfr[ni], acc[mi][ni], 0, 0, 0);
  }

#pragma unroll
  for (int mi = 0; mi < 2; ++mi) {
    int mrow0 = bm + wm * 32 + mi * 16 + (lane >> 4) * 4;
#pragma unroll
    for (int j = 0; j < 4; ++j) {
      int m = mrow0 + j;
      if (m < M) {
        float dv = dinv[m];
#pragma unroll
        for (int ni = 0; ni < 8; ++ni)
          __builtin_nontemporal_store(f2bf(acc[mi][ni][j] * dv),
                                      G + (size_t)m * 256 + wn * 128 + ni * 16 + l15);
      }
    }
  }
}

// ---------------- GEMM2: g2 = dinv .* (hid @ W2), tile 64x128, 256 thr ----------------

__global__ __launch_bounds__(256) void k_gemm2(
    const unsigned short* __restrict__ A, const unsigned short* __restrict__ Bt,
    const float* __restrict__ dinv, unsigned short* __restrict__ G, int M) {
  const int K = 256;
  __shared__ short lA[64 * 32];
  __shared__ short lB[128 * 32];
  int tid = threadIdx.x;
  int wid = tid >> 6, lane = tid & 63;
  int wm = wid >> 1, wn = wid & 1;
  int l15 = lane & 15;
  int lkg = (lane >> 4) * 8;
  int bm = blockIdx.x * 64;

  f32x4 acc[2][4] = {};

  for (int kt = 0; kt < 8; ++kt) {
    int k0 = kt * 32;
    __syncthreads();
    {
      int r = tid >> 2, kc = (tid & 3) * 8;
      int gr = bm + r;
      s16x8 v = {0, 0, 0, 0, 0, 0, 0, 0};
      if (gr < M) v = *(const s16x8*)(A + (size_t)gr * K + k0 + kc);
      *(s16x8*)(&lA[r * 32 + swz4(r, kc)]) = v;
    }
#pragma unroll
    for (int h = 0; h < 2; ++h) {
      int cid = tid + h * 256;
      int n = cid >> 2, kc = (cid & 3) * 8;
      s16x8 v = *(const s16x8*)(Bt + (size_t)n * K + k0 + kc);
      *(s16x8*)(&lB[n * 32 + swz4(n, kc)]) = v;
    }
    __syncthreads();

    s16x8 af[2], bfr[4];
#pragma unroll
    for (int mi = 0; mi < 2; ++mi) {
      int r = wm * 32 + mi * 16 + l15;
      af[mi] = *(const s16x8*)(&lA[r * 32 + swz4(r, lkg)]);
    }
#pragma unroll
    for (int ni = 0; ni < 4; ++ni) {
      int c = wn * 64 + ni * 16 + l15;
      bfr[ni] = *(const s16x8*)(&lB[c * 32 + swz4(c, lkg)]);
    }
#pragma unroll
    for (int mi = 0; mi < 2; ++mi)
#pragma unroll
      for (int ni = 0; ni < 4; ++ni)
        acc[mi][ni] = __builtin_amdgcn_mfma_f32_16x16x32_bf16(af[mi], bfr[ni], acc[mi][ni], 0, 0, 0);
  }

#pragma unroll
  for (int mi = 0; mi < 2; ++mi) {
    int mrow0 = bm + wm * 32 + mi * 16 + (lane >> 4) * 4;
#pragma unroll
    for (int j = 0; j < 4; ++j) {
      int m = mrow0 + j;
      if (m < M) {
        float dv = dinv[m];
#pragma unroll
        for (int ni = 0; ni < 4; ++ni)
          __builtin_nontemporal_store(f2bf(acc[mi][ni][j] * dv),
                                      G + (size_t)m * 128 + wn * 64 + ni * 16 + l15);
      }
    }
  }
}

// ---------------- agg layer 1: 256 feats (512B rows), single pass ----------------

__global__ __launch_bounds__(256) void k_agg256(
    const unsigned short* __restrict__ G, const int* __restrict__ rowptr,
    const int* __restrict__ col, const float* __restrict__ dinv,
    const float* __restrict__ bias, unsigned short* __restrict__ H, int M) {
  int lane = threadIdx.x & 63;
  int v = (blockIdx.x << 2) + (threadIdx.x >> 6);
  if (v >= M) return;
  int slot = lane >> 5;              // 0..1
  int l32 = lane & 31;
  int boff = l32 * 16;
  const char* Gb = (const char*)G;
  f32x2 a[4] = {};
  if (slot == 0) {
    uint4 w = *(const uint4*)(Gb + (((unsigned)v) << 9) + boff);
    acc2(a[0], w.x); acc2(a[1], w.y); acc2(a[2], w.z); acc2(a[3], w.w);
  }
  int jb = rowptr[v], je = rowptr[v + 1];
  int j = jb;
  for (; j + 4 <= je; j += 4) {
    unsigned u0 = (unsigned)__builtin_nontemporal_load(col + j + slot);
    unsigned u1 = (unsigned)__builtin_nontemporal_load(col + j + 2 + slot);
    uint4 w0 = *(const uint4*)(Gb + (u0 << 9) + boff);
    uint4 w1 = *(const uint4*)(Gb + (u1 << 9) + boff);
    acc2(a[0], w0.x); acc2(a[1], w0.y); acc2(a[2], w0.z); acc2(a[3], w0.w);
    acc2(a[0], w1.x); acc2(a[1], w1.y); acc2(a[2], w1.z); acc2(a[3], w1.w);
  }
  for (; j + 2 <= je; j += 2) {
    unsigned u = (unsigned)__builtin_nontemporal_load(col + j + slot);
    uint4 w = *(const uint4*)(Gb + (u << 9) + boff);
    acc2(a[0], w.x); acc2(a[1], w.y); acc2(a[2], w.z); acc2(a[3], w.w);
  }
  if (j < je && slot == 0) {
    unsigned u = (unsigned)__builtin_nontemporal_load(col + j);
    uint4 w = *(const uint4*)(Gb + (u << 9) + boff);
    acc2(a[0], w.x); acc2(a[1], w.y); acc2(a[2], w.z); acc2(a[3], w.w);
  }
#pragma unroll
  for (int k = 0; k < 4; ++k) {
    a[k].x += __shfl_xor(a[k].x, 32, 64);
    a[k].y += __shfl_xor(a[k].y, 32, 64);
  }
  if (slot == 0) {
    float dv = dinv[v];
    const float* bp = bias + l32 * 8;
    u16x8 o;
#pragma unroll
    for (int k = 0; k < 4; ++k) {
      o[2 * k]     = f2bf(fmaxf(fmaf(dv, a[k].x, bp[2 * k]),     0.f));
      o[2 * k + 1] = f2bf(fmaxf(fmaf(dv, a[k].y, bp[2 * k + 1]), 0.f));
    }
    __builtin_nontemporal_store(o, (u16x8*)(H + (size_t)v * 256 + l32 * 8));
  }
}

// ---------------- agg layer 2: 128 feats (256B rows), single pass, fp32 out ----------------

__global__ __launch_bounds__(256) void k_agg128(
    const unsigned short* __restrict__ G, const int* __restrict__ rowptr,
    const int* __restrict__ col, const float* __restrict__ dinv,
    const float* __restrict__ bias, float* __restrict__ Out, int M) {
  int lane = threadIdx.x & 63;
  int v = (blockIdx.x << 2) + (threadIdx.x >> 6);
  if (v >= M) return;
  int slot = lane >> 4;              // 0..3
  int l16 = lane & 15;
  int boff = l16 * 16;
  const char* Gb = (const char*)G;
  f32x2 a[4] = {};
  if (slot == 0) {
    uint4 w = *(const uint4*)(Gb + (((unsigned)v) << 8) + boff);
    acc2(a[0], w.x); acc2(a[1], w.y); acc2(a[2], w.z); acc2(a[3], w.w);
  }
  int jb = rowptr[v], je = rowptr[v + 1];
  int j = jb;
  for (; j + 8 <= je; j += 8) {
    unsigned u0 = (unsigned)__builtin_nontemporal_load(col + j + slot);
    unsigned u1 = (unsigned)__builtin_nontemporal_load(col + j + 4 + slot);
    uint4 w0 = *(const uint4*)(Gb + (u0 << 8) + boff);
    uint4 w1 = *(const uint4*)(Gb + (u1 << 8) + boff);
    acc2(a[0], w0.x); acc2(a[1], w0.y); acc2(a[2], w0.z); acc2(a[3], w0.w);
    acc2(a[0], w1.x); acc2(a[1], w1.y); acc2(a[2], w1.z); acc2(a[3], w1.w);
  }
  for (; j + 4 <= je; j += 4) {
    unsigned u = (unsigned)__builtin_nontemporal_load(col + j + slot);
    uint4 w = *(const uint4*)(Gb + (u << 8) + boff);
    acc2(a[0], w.x); acc2(a[1], w.y); acc2(a[2], w.z); acc2(a[3], w.w);
  }
  int rem = je - j;
  if (slot < rem) {
    unsigned u = (unsigned)__builtin_nontemporal_load(col + j + slot);
    uint4 w = *(const uint4*)(Gb + (u << 8) + boff);
    acc2(a[0], w.x); acc2(a[1], w.y); acc2(a[2], w.z); acc2(a[3], w.w);
  }
#pragma unroll
  for (int k = 0; k < 4; ++k) {
    a[k].x += __shfl_xor(a[k].x, 16, 64);
    a[k].y += __shfl_xor(a[k].y, 16, 64);
    a[k].x += __shfl_xor(a[k].x, 32, 64);
    a[k].y += __shfl_xor(a[k].y, 32, 64);
  }
  if (slot == 0) {
    float dv = dinv[v];
    const float* bp = bias + l16 * 8;
    f32x4 r0, r1;
    r0[0] = fmaxf(fmaf(dv, a[0].x, bp[0]), 0.f);
    r0[1] = fmaxf(fmaf(dv, a[0].y, bp[1]), 0.f);
    r0[2] = fmaxf(fmaf(dv, a[1].x, bp[2]), 0.f);
    r0[3] = fmaxf(fmaf(dv, a[1].y, bp[3]), 0.f);
    r1[0] = fmaxf(fmaf(dv, a[2].x, bp[4]), 0.f);
    r1[1] = fmaxf(fmaf(dv, a[2].y, bp[5]), 0.f);
    r1[2] = fmaxf(fmaf(dv, a[3].x, bp[6]), 0.f);
    r1[3] = fmaxf(fmaf(dv, a[3].y, bp[7]), 0.f);
    float* op = Out + (size_t)v * 128 + l16 * 8;
    __builtin_nontemporal_store(r0, (f32x4*)op);
    __builtin_nontemporal_store(r1, (f32x4*)(op + 4));
  }
}

// ---------------- launch ----------------

extern "C" void kernel_launch(void* const* d_in, const int* in_sizes, int n_in,
                              void* d_out, int out_size, void* d_ws, size_t ws_size,
                              hipStream_t stream) {
  const float* x  = (const float*)d_in[0];
  const float* W1 = (const float*)d_in[1];
  const float* b1 = (const float*)d_in[2];
  const float* W2 = (const float*)d_in[3];
  const float* b2 = (const float*)d_in[4];
  const int*   ei = (const int*)d_in[5];

  const int D_IN = 256, D_HID = 256, D_OUT = 128;
  const int M = in_sizes[0] / D_IN;    // 100000
  const int E = in_sizes[5] / 2;       // 3200000
  const int* src = ei;
  const int* dst = ei + E;

  char* p = (char*)d_ws;
  auto alloc = [&](size_t bytes) { void* r = (void*)p; p += (bytes + 255) & ~(size_t)255; return r; };
  float* dinv = (float*)alloc((size_t)M * 4);
  int* rowptr = (int*)alloc((size_t)(M + 1) * 4);
  int* bcnt   = (int*)alloc(NBUCK_PAD * 4);
  int* bptr   = (int*)alloc((NBUCK_PAD + 1) * 4);
  int* bcur   = (int*)alloc(NBUCK_PAD * 4);
  int* colx   = (int*)alloc((size_t)E * 4);
  unsigned short* w1t = (unsigned short*)alloc((size_t)D_HID * D_IN * 2);
  unsigned short* w2t = (unsigned short*)alloc((size_t)D_OUT * D_HID * 2);
  unsigned short* g1  = (unsigned short*)alloc((size_t)M * D_HID * 2);   // [M][256]
  unsigned short* hid = (unsigned short*)alloc((size_t)M * D_HID * 2);   // [M][256]
  unsigned short* g2  = (unsigned short*)alloc((size_t)M * D_OUT * 2);   // [M][128]
  unsigned int* binned = (unsigned int*)g1;   // g1 written only after k_csr consumed binned

  int nbuck = (M + 127) >> 7;                     // 782
  int nbin  = (E + BIN_CHUNK - 1) / BIN_CHUNK;    // 391
  int nb4   = (M + 3) / 4;
  int ngm   = (M + 63) / 64;                      // 1563

  hipMemsetAsync(bcnt, 0, NBUCK_PAD * 4, stream);
  k_hist <<<104, 256, 0, stream>>>(dst, bcnt, E);
  k_bscan<<<1, NBUCK_PAD, 0, stream>>>(bcnt, bptr, bcur, rowptr, M, E);
  k_bin  <<<nbin, 256, 0, stream>>>(src, dst, bcur, binned, E);
  k_csr  <<<nbuck, 256, 0, stream>>>(binned, bptr, rowptr, dinv, colx, M);

  k_cvt_w<<<(256 * 256 + 256 * 128 + 255) / 256, 256, 0, stream>>>(W1, W2, w1t, w2t);

  k_gemm1 <<<ngm, 256, 0, stream>>>(x, w1t, dinv, g1, M);
  k_agg256<<<nb4, 256, 0, stream>>>(g1, rowptr, colx, dinv, b1, hid, M);
  k_gemm2 <<<ngm, 256, 0, stream>>>(hid, w2t, dinv, g2, M);
  k_agg128<<<nb4, 256, 0, stream>>>(g2, rowptr, colx, dinv, b2, (float*)d_out, M);
}